// Round 7
// baseline (441.760 us; speedup 1.0000x reference)
//
#include <hip/hip_runtime.h>
#include <hip/hip_cooperative_groups.h>

namespace cg = cooperative_groups;

// MobileMQA: B=8, C=256, H=W=64, NUM_HEADS=4, hd=64, ds=2
// R14: ONE cooperative launch. Evidence: total - k_fused = 112-117us constant
//      across R8-R13 regardless of preamble structure (even deleting a kernel)
//      -> dominated by launch/serialization overhead, not kernel work.
//      k_all: Phase A (x read ONCE: transpose->xT + stats from same regs +
//      weight convert) | grid.sync | Phase B (nt<32: KV gemm into kst/vst
//      alias; all: Q-proj) | grid.sync | Phase C (R13 attention+WO verbatim).
//      512 blocks x 57.4KB LDS = exactly 2 blocks/CU co-resident.
//      Fallback to R13 3-kernel path if cooperative launch fails.

#define CNT_INV (1.0f/1048576.0f)
#define EPSV 1e-5f
#define QSCALE 0.18033688f   // 0.125 * log2(e): folded into Q; exp = v_exp_f32(S)

// workspace layout (float offsets)
#define WS_STATS 0                    // 64
#define WS_XNT   64                   // bf16 xT  [b][n][c]  = 4,194,304 f
#define WS_K     5242944              // bf16 k   [b][m][d]  = 262,144 f
#define WS_V     5505088              // bf16 v windows      = 262,144 f
#define WS_WQB   5767232              // bf16 wq  [o][c]     = 32,768 f
#define WS_WKV   5800000              // bf16 [wk;wv]        = 16,384 f
#define WS_WOB   5816384              // bf16 wo  [o][c]     = 32,768 f

typedef __attribute__((ext_vector_type(8))) short bf8_t;   // 8 bf16 MFMA A/B frag
typedef __attribute__((ext_vector_type(4))) float f4_t;    // MFMA C/D frag

static __device__ __forceinline__ unsigned fbits(float f) {
  union { float f; unsigned u; } v; v.f = f; return v.u;
}
static __device__ __forceinline__ unsigned short f2bf(float f) {  // RNE-ish
  unsigned u = fbits(f);
  return (unsigned short)((u + 0x7fffu + ((u >> 16) & 1u)) >> 16);
}
static __device__ __forceinline__ unsigned pk_rnd(float a, float b) {
  return __builtin_amdgcn_perm(fbits(b) + 0x8000u, fbits(a) + 0x8000u, 0x07060302u);
}
static __device__ __forceinline__ unsigned pk_tr(float a, float b) {
  return __builtin_amdgcn_perm(fbits(b), fbits(a), 0x07060302u);
}
static __device__ __forceinline__ float bf2f(unsigned short h) {
  union { unsigned u; float f; } v; v.u = ((unsigned)h) << 16; return v.f;
}
static __device__ __forceinline__ float fexp2(float x) {   // 2^x, raw v_exp_f32
  float r; asm("v_exp_f32 %0, %1" : "=v"(r) : "v"(x)); return r;
}

// affine on a raw-x bf8 frag: out[j] = a8[j]*x[j] + b8[j]
static __device__ __forceinline__ bf8_t affine8(bf8_t r, const float* a8, const float* b8) {
  union { bf8_t v; unsigned short u[8]; unsigned w[4]; } in, out;
  in.v = r;
#pragma unroll
  for (int i = 0; i < 4; ++i) {
    float lo = fmaf(bf2f(in.u[2 * i]),     a8[2 * i],     b8[2 * i]);
    float hi = fmaf(bf2f(in.u[2 * i + 1]), a8[2 * i + 1], b8[2 * i + 1]);
    out.w[i] = pk_rnd(lo, hi);
  }
  return out.v;
}

// pooled+affine frag: out[j] = a4[j]*(x00+x01+x10+x11)[j] + b8[j]  (a4 = a/4)
static __device__ __forceinline__ bf8_t pool_affine(bf8_t s00, bf8_t s01, bf8_t s10, bf8_t s11,
                                                    const float* a4, const float* b8) {
  union { bf8_t v; unsigned short u[8]; unsigned w[4]; } x00, x01, x10, x11, out;
  x00.v = s00; x01.v = s01; x10.v = s10; x11.v = s11;
#pragma unroll
  for (int i = 0; i < 4; ++i) {
    float lo = (bf2f(x00.u[2 * i]) + bf2f(x01.u[2 * i])) +
               (bf2f(x10.u[2 * i]) + bf2f(x11.u[2 * i]));
    float hi = (bf2f(x00.u[2 * i + 1]) + bf2f(x01.u[2 * i + 1])) +
               (bf2f(x10.u[2 * i + 1]) + bf2f(x11.u[2 * i + 1]));
    lo = fmaf(lo, a4[2 * i],     b8[2 * i]);
    hi = fmaf(hi, a4[2 * i + 1], b8[2 * i + 1]);
    out.w[i] = pk_rnd(lo, hi);
  }
  return out.v;
}

// ==================== R14 merged cooperative kernel ====================
__global__ __launch_bounds__(256) void k_all(const float* __restrict__ x,
                                             const float* __restrict__ gnw,
                                             const float* __restrict__ gnb,
                                             const float* __restrict__ wq,
                                             const float* __restrict__ wk,
                                             const float* __restrict__ wv,
                                             const float* __restrict__ wo,
                                             const float* __restrict__ gamma,
                                             float* __restrict__ stats,
                                             unsigned short* __restrict__ wqb,
                                             unsigned short* __restrict__ wkvb,
                                             unsigned short* __restrict__ wob,
                                             unsigned short* __restrict__ xtb,
                                             unsigned short* __restrict__ kbf,
                                             unsigned short* __restrict__ vtbf,
                                             float* __restrict__ outp) {
  __shared__ __align__(16) unsigned short smem[20480];   // 40,960 B (T / qst / plds / aos)
  __shared__ __align__(16) unsigned short kst[2][2048];  //  8,192 B (kv0 alias / K dbuf)
  __shared__ __align__(16) unsigned short vst[2][2048];  //  8,192 B (kv1 alias / V dbuf)
  __shared__ float red[8];
  cg::grid_group grid = cg::this_grid();
  const int t = threadIdx.x;
  const int bid = blockIdx.x;            // 0..511
  const int b = bid >> 6, nt = bid & 63;
  const int w = t >> 6, l = t & 63, lane16 = l & 15, quad = l >> 4;

  // ======== Phase A: x->xT transpose + stats (same reads) + weight convert ========
  {
    unsigned short (*T)[72] = (unsigned short (*)[72])smem;
    float s = 0.f, s2 = 0.f;
    const int n4 = (t & 31) * 4, cl = t >> 5;
    const int wswz = t & 7;
    for (int sub = 0; sub < 2; ++sub) {
      const int tile = nt * 2 + sub;                 // 0..127 within batch b
      const int c0 = (tile >> 5) * 64, n0a = (tile & 31) * 128;
#pragma unroll
      for (int p = 0; p < 8; ++p) {
        const int c = c0 + p * 8 + cl;
        const int pc = (p ^ wswz) * 8 + cl;
        float4 v = *(const float4*)&x[(size_t)(b * 256 + c) * 4096 + n0a + n4];
        s  += (v.x + v.y) + (v.z + v.w);
        s2 += (v.x * v.x + v.y * v.y) + (v.z * v.z + v.w * v.w);
        T[n4 + 0][pc] = f2bf(v.x);
        T[n4 + 1][pc] = f2bf(v.y);
        T[n4 + 2][pc] = f2bf(v.z);
        T[n4 + 3][pc] = f2bf(v.w);
      }
      __syncthreads();
      {
        const int r = t >> 1, cb4 = (t & 1) * 4;
        const int rswz = (t >> 3) & 7;
        unsigned short* dst = xtb + ((size_t)b * 4096 + n0a + r) * 256 + c0 + cb4 * 8;
#pragma unroll
        for (int u = 0; u < 4; ++u)
          *(uint4*)(dst + u * 8) = *(const uint4*)&T[r][((cb4 + u) ^ rswz) * 8];
      }
      __syncthreads();
    }
#pragma unroll
    for (int o = 32; o > 0; o >>= 1) {
      s  += __shfl_down(s, o);
      s2 += __shfl_down(s2, o);
    }
    if ((t & 63) == 0) { red[w] = s; red[4 + w] = s2; }
    __syncthreads();
    if (t == 0) {
      atomicAdd(&stats[b * 2 + 0], red[0] + red[1] + red[2] + red[3]);
      atomicAdd(&stats[b * 2 + 1], red[4] + red[5] + red[6] + red[7]);
    }
    const int base = bid * 320;
    for (int k = t; k < 320; k += 256) {
      const int idx = base + k;
      if (idx < 65536) wqb[idx] = f2bf(wq[idx]);
      else if (idx < 81920) wkvb[idx - 65536] = f2bf(wk[idx - 65536]);
      else if (idx < 98304) wkvb[idx - 65536] = f2bf(wv[idx - 81920]);
      else wob[idx - 98304] = f2bf(wo[idx - 98304]);
    }
  }
  __threadfence();
  grid.sync();

  // ======== Phase B: KV gemm (nt<32) + Q-proj (all) ========
  const float mu = stats[b * 2 + 0] * CNT_INV;
  const float rstd = rsqrtf(stats[b * 2 + 1] * CNT_INV - mu * mu + EPSV);

  if (nt < 32) {  // KV gemm for m0 = nt*32, outputs in R13 layouts
    unsigned short (*kv0)[72] = (unsigned short (*)[72])(&kst[0][0]);  // K [32 m][72]
    unsigned short (*kv1)[40] = (unsigned short (*)[40])(&vst[0][0]);  // V [64 d][40]
    const int m0 = nt * 32;
    const int kvsel = w >> 1, wh = w & 1;
    const unsigned short* Abase = wkvb + (size_t)kvsel * 16384 +
                                  (size_t)(wh * 32 + lane16) * 256 + quad * 8;
    const unsigned short* B00[2];
#pragma unroll
    for (int mg = 0; mg < 2; ++mg) {
      const int m = m0 + mg * 16 + lane16;
      const int nb = (m >> 5) * 128 + (m & 31) * 2;
      B00[mg] = xtb + ((size_t)b * 4096 + nb) * 256 + quad * 8;
    }
    f4_t acc[2][2];
#pragma unroll
    for (int i = 0; i < 2; ++i)
#pragma unroll
      for (int j = 0; j < 2; ++j) acc[i][j] = (f4_t){0.f, 0.f, 0.f, 0.f};
    for (int kc = 0; kc < 256; kc += 32) {
      const int cb = kc + quad * 8;
      float4 g0 = *(const float4*)&gnw[cb];
      float4 g1 = *(const float4*)&gnw[cb + 4];
      float4 h0 = *(const float4*)&gnb[cb];
      float4 h1 = *(const float4*)&gnb[cb + 4];
      float a4[8], b8[8];
      const float gg[8] = {g0.x, g0.y, g0.z, g0.w, g1.x, g1.y, g1.z, g1.w};
      const float hh[8] = {h0.x, h0.y, h0.z, h0.w, h1.x, h1.y, h1.z, h1.w};
#pragma unroll
      for (int j = 0; j < 8; ++j) {
        const float a = gg[j] * rstd;
        a4[j] = a * 0.25f;
        b8[j] = hh[j] - mu * a;
      }
      bf8_t Bf[2];
#pragma unroll
      for (int mg = 0; mg < 2; ++mg) {
        const unsigned short* p = B00[mg] + kc;
        bf8_t s00 = *(const bf8_t*)p;
        bf8_t s01 = *(const bf8_t*)(p + 256);
        bf8_t s10 = *(const bf8_t*)(p + 64 * 256);
        bf8_t s11 = *(const bf8_t*)(p + 65 * 256);
        Bf[mg] = pool_affine(s00, s01, s10, s11, a4, b8);
      }
      bf8_t A[2];
#pragma unroll
      for (int og = 0; og < 2; ++og) A[og] = *(const bf8_t*)(Abase + (size_t)og * 16 * 256 + kc);
#pragma unroll
      for (int og = 0; og < 2; ++og)
#pragma unroll
        for (int mg = 0; mg < 2; ++mg)
          acc[og][mg] = __builtin_amdgcn_mfma_f32_16x16x32_bf16(A[og], Bf[mg], acc[og][mg], 0, 0, 0);
    }
    if (w < 2) {  // K -> kv0[m][d]
#pragma unroll
      for (int og = 0; og < 2; ++og)
#pragma unroll
        for (int mg = 0; mg < 2; ++mg) {
          uint2 p;
          p.x = pk_rnd(acc[og][mg][0], acc[og][mg][1]);
          p.y = pk_rnd(acc[og][mg][2], acc[og][mg][3]);
          *(uint2*)&kv0[mg * 16 + lane16][wh * 32 + og * 16 + quad * 4] = p;
        }
    } else {      // V -> kv1[d][m]
#pragma unroll
      for (int og = 0; og < 2; ++og)
#pragma unroll
        for (int mg = 0; mg < 2; ++mg) {
          const int d0 = wh * 32 + og * 16 + quad * 4;
#pragma unroll
          for (int r = 0; r < 4; ++r)
            kv1[d0 + r][mg * 16 + lane16] = f2bf(acc[og][mg][r]);
        }
    }
    __syncthreads();
    {  // coalesced writeout
      const int rowk = t >> 3, ch = t & 7, e = rowk & 7;
      *(uint4*)(kbf + (size_t)b * 65536 + (size_t)(m0 + rowk) * 64 + ((ch ^ e) * 8)) =
          *(const uint4*)&kv0[rowk][ch * 8];
      const int rowd = t >> 2, q = t & 3;
      *(uint4*)(vtbf + (size_t)b * 65536 + (size_t)nt * 2048 + (size_t)rowd * 32 + q * 8) =
          *(const uint4*)&kv1[rowd][q * 8];
    }
    __syncthreads();
  }

  // ---- Q-proj (all blocks): 64q x 64d per head-wave, B = affine(xT) ----
  const int n0 = nt * 64;
  const int h = w;
  unsigned short* qst = smem + w * 4608;                               // [64][72]
  unsigned short (*plds)[64][40] = (unsigned short (*)[64][40])(smem + w * 5120);
  unsigned short (*aos)[264] = (unsigned short (*)[264])smem;
  {
    const unsigned short* Abase = wqb + (size_t)(h * 64 + lane16) * 256 + quad * 8;
    const unsigned short* Bbase = xtb + ((size_t)b * 4096 + n0 + lane16) * 256 + quad * 8;
    f4_t qacc[4][4];
#pragma unroll
    for (int i = 0; i < 4; ++i)
#pragma unroll
      for (int j = 0; j < 4; ++j) qacc[i][j] = (f4_t){0.f, 0.f, 0.f, 0.f};
    for (int kc = 0; kc < 256; kc += 32) {
      const int cb = kc + quad * 8;
      float4 g0 = *(const float4*)&gnw[cb];
      float4 g1 = *(const float4*)&gnw[cb + 4];
      float4 h0 = *(const float4*)&gnb[cb];
      float4 h1 = *(const float4*)&gnb[cb + 4];
      float a8[8], b8[8];
      const float gg[8] = {g0.x, g0.y, g0.z, g0.w, g1.x, g1.y, g1.z, g1.w};
      const float hh[8] = {h0.x, h0.y, h0.z, h0.w, h1.x, h1.y, h1.z, h1.w};
#pragma unroll
      for (int j = 0; j < 8; ++j) {
        a8[j] = gg[j] * rstd;
        b8[j] = hh[j] - mu * a8[j];
      }
      bf8_t A[4], Bf[4];
#pragma unroll
      for (int og = 0; og < 4; ++og) A[og] = *(const bf8_t*)(Abase + (size_t)og * 16 * 256 + kc);
#pragma unroll
      for (int ng = 0; ng < 4; ++ng) {
        bf8_t raw = *(const bf8_t*)(Bbase + (size_t)ng * 16 * 256 + kc);
        Bf[ng] = affine8(raw, a8, b8);
      }
#pragma unroll
      for (int og = 0; og < 4; ++og)
#pragma unroll
        for (int ng = 0; ng < 4; ++ng)
          qacc[og][ng] = __builtin_amdgcn_mfma_f32_16x16x32_bf16(A[og], Bf[ng], qacc[og][ng], 0, 0, 0);
    }
#pragma unroll
    for (int og = 0; og < 4; ++og)
#pragma unroll
      for (int ng = 0; ng < 4; ++ng) {
        uint2 p;
        p.x = pk_rnd(qacc[og][ng][0] * QSCALE, qacc[og][ng][1] * QSCALE);
        p.y = pk_rnd(qacc[og][ng][2] * QSCALE, qacc[og][ng][3] * QSCALE);
        *(uint2*)&qst[(ng * 16 + lane16) * 72 + og * 16 + quad * 4] = p;
      }
  }
  bf8_t Qf[4][2];
#pragma unroll
  for (int qg = 0; qg < 4; ++qg)
#pragma unroll
    for (int dc = 0; dc < 2; ++dc)
      Qf[qg][dc] = *(const bf8_t*)&qst[(qg * 16 + lane16) * 72 + dc * 32 + quad * 8];
  __syncthreads();
  __threadfence();
  grid.sync();   // K/V (all m-tiles, all b) + everyone's Q ready

  // ======== Phase C: attention + WO + residual (R13 verbatim) ========
  const int sw = w & 1;
  const unsigned short* sbase = (w < 2) ? (kbf + (size_t)b * 65536) : (vtbf + (size_t)b * 65536);
  unsigned short* sdst0 = ((w < 2) ? &kst[0][0] : &vst[0][0]) + sw * 1024 + l * 8;
  unsigned short* sdst1 = ((w < 2) ? &kst[1][0] : &vst[1][0]) + sw * 1024 + l * 8;

#define STAGE_ISSUE(WIN, R0, R1)                                              \
  { const unsigned short* sp = sbase + (size_t)(WIN) * 2048 + sw * 1024 + l * 8; \
    R0 = *(const uint4*)sp; R1 = *(const uint4*)(sp + 512); }
#define STAGE_WRITE(DP, R0, R1)                                               \
  { *(uint4*)(DP) = R0; *(uint4*)((DP) + 512) = R1; }
#define READ_K(BUF, KREG)                                                     \
  {                                                                           \
    _Pragma("unroll")                                                         \
    for (int s = 0; s < 2; ++s) {                                             \
      _Pragma("unroll")                                                       \
      for (int dc = 0; dc < 2; ++dc)                                          \
        KREG[s][dc] = *(const bf8_t*)&kst[BUF][(s * 16 + lane16) * 64 +       \
                                              (((dc * 4 + quad) ^ (lane16 & 7)) * 8)]; \
    }                                                                         \
  }
#define READ_V(BUF, VREG)                                                     \
  {                                                                           \
    _Pragma("unroll")                                                         \
    for (int dg = 0; dg < 4; ++dg)                                            \
      VREG[dg] = *(const bf8_t*)&vst[BUF][(dg * 16 + lane16) * 32 + quad * 8]; \
  }
#define SSTEP(KREG, BUF)                                                      \
  {                                                                           \
    _Pragma("unroll")                                                         \
    for (int qg = 0; qg < 4; ++qg) {                                          \
      _Pragma("unroll")                                                       \
      for (int s = 0; s < 2; ++s) {                                           \
        f4_t S = (f4_t){0.f, 0.f, 0.f, 0.f};                                  \
        S = __builtin_amdgcn_mfma_f32_16x16x32_bf16(KREG[s][0], Qf[qg][0], S, 0, 0, 0); \
        S = __builtin_amdgcn_mfma_f32_16x16x32_bf16(KREG[s][1], Qf[qg][1], S, 0, 0, 0); \
        float e0 = fexp2(S[0]);                                               \
        float e1 = fexp2(S[1]);                                               \
        float e2 = fexp2(S[2]);                                               \
        float e3 = fexp2(S[3]);                                               \
        uint2 p; p.x = pk_tr(e0, e1); p.y = pk_tr(e2, e3);                    \
        *(uint2*)&plds[BUF][qg * 16 + lane16][s * 16 + quad * 4] = p;         \
      }                                                                       \
    }                                                                         \
  }

  f4_t O[4][4];
#pragma unroll
  for (int dg = 0; dg < 4; ++dg)
#pragma unroll
    for (int qg = 0; qg < 4; ++qg) O[dg][qg] = (f4_t){0.f, 0.f, 0.f, 0.f};
  f4_t O4[4];
#pragma unroll
  for (int qg = 0; qg < 4; ++qg) O4[qg] = (f4_t){0.f, 0.f, 0.f, 0.f};
  const short onebf = (lane16 == 0) ? (short)0x3F80 : (short)0;
  const bf8_t Aone = {onebf, onebf, onebf, onebf, onebf, onebf, onebf, onebf};

  {  // prologue: stage windows 0 and 1
    uint4 a0, a1, b0, b1;
    STAGE_ISSUE(0, a0, a1);
    STAGE_ISSUE(1, b0, b1);
    STAGE_WRITE(sdst0, a0, a1);
    STAGE_WRITE(sdst1, b0, b1);
  }
  __syncthreads();

  bf8_t Kc[2][2], Vc[4];
  READ_K(0, Kc);
  SSTEP(Kc, 0);
  READ_V(0, Vc);
  __syncthreads();

  for (int it = 1; it < 32; ++it) {
    const int cur = it & 1, pb = cur ^ 1;
    uint4 g0, g1;
    if (it < 31) STAGE_ISSUE(it + 1, g0, g1);
    bf8_t Pf[4];
#pragma unroll
    for (int qg = 0; qg < 4; ++qg)
      Pf[qg] = *(const bf8_t*)&plds[pb][qg * 16 + lane16][quad * 8];
    READ_K(cur, Kc);
    bf8_t Vn[4];
    READ_V(cur, Vn);
    __builtin_amdgcn_s_setprio(1);
#pragma unroll
    for (int dg = 0; dg < 4; ++dg)
#pragma unroll
      for (int qg = 0; qg < 4; ++qg)
        O[dg][qg] = __builtin_amdgcn_mfma_f32_16x16x32_bf16(Vc[dg], Pf[qg], O[dg][qg], 0, 0, 0);
#pragma unroll
    for (int qg = 0; qg < 4; ++qg)
      O4[qg] = __builtin_amdgcn_mfma_f32_16x16x32_bf16(Aone, Pf[qg], O4[qg], 0, 0, 0);
    __builtin_amdgcn_s_setprio(0);
    SSTEP(Kc, cur);
#pragma unroll
    for (int dg = 0; dg < 4; ++dg) Vc[dg] = Vn[dg];
    if (it < 31) STAGE_WRITE((cur ? sdst0 : sdst1), g0, g1);
    __syncthreads();
  }
  {  // epilogue: PV(31), P in buf 1
    bf8_t Pf[4];
#pragma unroll
    for (int qg = 0; qg < 4; ++qg)
      Pf[qg] = *(const bf8_t*)&plds[1][qg * 16 + lane16][quad * 8];
    __builtin_amdgcn_s_setprio(1);
#pragma unroll
    for (int dg = 0; dg < 4; ++dg)
#pragma unroll
      for (int qg = 0; qg < 4; ++qg)
        O[dg][qg] = __builtin_amdgcn_mfma_f32_16x16x32_bf16(Vc[dg], Pf[qg], O[dg][qg], 0, 0, 0);
#pragma unroll
    for (int qg = 0; qg < 4; ++qg)
      O4[qg] = __builtin_amdgcn_mfma_f32_16x16x32_bf16(Aone, Pf[qg], O4[qg], 0, 0, 0);
    __builtin_amdgcn_s_setprio(0);
  }
#undef SSTEP
#undef STAGE_ISSUE
#undef STAGE_WRITE
#undef READ_K
#undef READ_V

  float rden[4];
#pragma unroll
  for (int qg = 0; qg < 4; ++qg) {
    float d = __shfl(O4[qg][0], lane16);
    rden[qg] = 1.f / d;
  }

  __syncthreads();
#pragma unroll
  for (int dg = 0; dg < 4; ++dg)
#pragma unroll
    for (int qg = 0; qg < 4; ++qg) {
      const int c0 = h * 64 + dg * 16 + quad * 4;
      uint2 p;
      p.x = pk_rnd(O[dg][qg][0] * rden[qg], O[dg][qg][1] * rden[qg]);
      p.y = pk_rnd(O[dg][qg][2] * rden[qg], O[dg][qg][3] * rden[qg]);
      *(uint2*)&aos[qg * 16 + lane16][c0] = p;
    }
  __syncthreads();

  {  // WO gemm from LDS + residual
    const unsigned short* Wbase = wob + (size_t)(w * 64 + lane16) * 256 + quad * 8;
    f4_t acc[4][4];
#pragma unroll
    for (int i = 0; i < 4; ++i)
#pragma unroll
      for (int j = 0; j < 4; ++j) acc[i][j] = (f4_t){0.f, 0.f, 0.f, 0.f};
    for (int kc = 0; kc < 256; kc += 32) {
      bf8_t A[4], Bf[4];
#pragma unroll
      for (int og = 0; og < 4; ++og) A[og] = *(const bf8_t*)(Wbase + (size_t)og * 16 * 256 + kc);
#pragma unroll
      for (int ng = 0; ng < 4; ++ng) Bf[ng] = *(const bf8_t*)&aos[ng * 16 + lane16][kc + quad * 8];
#pragma unroll
      for (int og = 0; og < 4; ++og)
#pragma unroll
        for (int ng = 0; ng < 4; ++ng)
          acc[og][ng] = __builtin_amdgcn_mfma_f32_16x16x32_bf16(A[og], Bf[ng], acc[og][ng], 0, 0, 0);
    }
#pragma unroll
    for (int og = 0; og < 4; ++og) {
      float4 g4 = *(const float4*)&gamma[w * 64 + og * 16 + quad * 4];
      const float g[4] = {g4.x, g4.y, g4.z, g4.w};
#pragma unroll
      for (int ng = 0; ng < 4; ++ng) {
        const int n = n0 + ng * 16 + lane16;
#pragma unroll
        for (int r = 0; r < 4; ++r) {
          const int o = w * 64 + og * 16 + quad * 4 + r;
          const size_t ix = ((size_t)(b * 256 + o)) * 4096 + n;
          outp[ix] = x[ix] + g[r] * acc[og][ng][r];
        }
      }
    }
  }
}

// ==================== R13 fallback kernels (unchanged) ====================
__global__ __launch_bounds__(256) void k_prep(const float* __restrict__ x,
                                              const float* __restrict__ wq,
                                              const float* __restrict__ wk,
                                              const float* __restrict__ wv,
                                              const float* __restrict__ wo,
                                              float* __restrict__ stats,
                                              unsigned short* __restrict__ wqb,
                                              unsigned short* __restrict__ wkvb,
                                              unsigned short* __restrict__ wob,
                                              unsigned short* __restrict__ xtb) {
  __shared__ unsigned short T[128][72];
  __shared__ float red[8];
  const int blk = blockIdx.x;
  const int t = threadIdx.x;
  if (blk < 512) {
    const int b = blk >> 6;
    const int chunk = blk & 63;
    const float4* xb = (const float4*)(x + (size_t)b * 1048576 + (size_t)chunk * 16384);
    float s = 0.f, s2 = 0.f;
#pragma unroll
    for (int it = 0; it < 16; ++it) {
      float4 v = xb[it * 256 + t];
      s  += v.x + v.y + v.z + v.w;
      s2 += v.x * v.x + v.y * v.y + v.z * v.z + v.w * v.w;
    }
#pragma unroll
    for (int o = 32; o > 0; o >>= 1) {
      s  += __shfl_down(s, o);
      s2 += __shfl_down(s2, o);
    }
    const int wid = t >> 6;
    if ((t & 63) == 0) { red[wid] = s; red[4 + wid] = s2; }
    __syncthreads();
    if (t == 0) {
      atomicAdd(&stats[b * 2 + 0], red[0] + red[1] + red[2] + red[3]);
      atomicAdd(&stats[b * 2 + 1], red[4] + red[5] + red[6] + red[7]);
    }
  } else if (blk < 1152) {
    const int idx = (blk - 512) * 256 + t;
    if (idx < 65536) wqb[idx] = f2bf(wq[idx]);
    else if (idx < 81920) wkvb[idx - 65536] = f2bf(wk[idx - 65536]);
    else if (idx < 98304) wkvb[idx - 65536] = f2bf(wv[idx - 81920]);
    else if (idx < 163840) wob[idx - 98304] = f2bf(wo[idx - 98304]);
  } else {
    const int idx = blk - 1152;
    const int hp = idx & 31, cq = (idx >> 5) & 3, b = idx >> 7;
    const int c0 = cq * 64, n0 = hp * 128;
    const int n4 = (t & 31) * 4, cl = t >> 5;
    const int wswz = t & 7;
#pragma unroll
    for (int p = 0; p < 8; ++p) {
      const int c = c0 + p * 8 + cl;
      const int pc = (p ^ wswz) * 8 + cl;
      float4 v = *(const float4*)&x[(size_t)(b * 256 + c) * 4096 + n0 + n4];
      T[n4 + 0][pc] = f2bf(v.x);
      T[n4 + 1][pc] = f2bf(v.y);
      T[n4 + 2][pc] = f2bf(v.z);
      T[n4 + 3][pc] = f2bf(v.w);
    }
    __syncthreads();
    {
      const int r = t >> 1, cb4 = (t & 1) * 4;
      const int rswz = (t >> 3) & 7;
      unsigned short* dst = xtb + ((size_t)b * 4096 + n0 + r) * 256 + c0 + cb4 * 8;
#pragma unroll
      for (int u = 0; u < 4; ++u)
        *(uint4*)(dst + u * 8) = *(const uint4*)&T[r][((cb4 + u) ^ rswz) * 8];
    }
  }
}

__global__ __launch_bounds__(256) void k_gemm_kv(const unsigned short* __restrict__ wkvb,
                                                 const unsigned short* __restrict__ xtb,
                                                 const float* __restrict__ gnw,
                                                 const float* __restrict__ gnb,
                                                 const float* __restrict__ stats,
                                                 unsigned short* __restrict__ kbf,
                                                 unsigned short* __restrict__ vtbf) {
  __shared__ __align__(16) unsigned short kv0[32][72];
  __shared__ __align__(16) unsigned short kv1[64][40];
  const int t = threadIdx.x;
  const int w = t >> 6, l = t & 63, lane16 = l & 15, quad = l >> 4;
  const int m0 = blockIdx.x * 32, b = blockIdx.y;
  const int kvsel = w >> 1, wh = w & 1;
  const float mu = stats[b * 2 + 0] * CNT_INV;
  const float rstd = rsqrtf(stats[b * 2 + 1] * CNT_INV - mu * mu + EPSV);
  const unsigned short* Abase = wkvb + (size_t)kvsel * 16384 +
                                (size_t)(wh * 32 + lane16) * 256 + quad * 8;
  const unsigned short* B00[2];
#pragma unroll
  for (int mg = 0; mg < 2; ++mg) {
    const int m = m0 + mg * 16 + lane16;
    const int nb = (m >> 5) * 128 + (m & 31) * 2;
    B00[mg] = xtb + ((size_t)b * 4096 + nb) * 256 + quad * 8;
  }
  f4_t acc[2][2];
#pragma unroll
  for (int i = 0; i < 2; ++i)
#pragma unroll
    for (int j = 0; j < 2; ++j) acc[i][j] = (f4_t){0.f, 0.f, 0.f, 0.f};
  for (int kc = 0; kc < 256; kc += 32) {
    const int cb = kc + quad * 8;
    float4 g0 = *(const float4*)&gnw[cb];
    float4 g1 = *(const float4*)&gnw[cb + 4];
    float4 h0 = *(const float4*)&gnb[cb];
    float4 h1 = *(const float4*)&gnb[cb + 4];
    float a4[8], b8[8];
    const float gg[8] = {g0.x, g0.y, g0.z, g0.w, g1.x, g1.y, g1.z, g1.w};
    const float hh[8] = {h0.x, h0.y, h0.z, h0.w, h1.x, h1.y, h1.z, h1.w};
#pragma unroll
    for (int j = 0; j < 8; ++j) {
      const float a = gg[j] * rstd;
      a4[j] = a * 0.25f;
      b8[j] = hh[j] - mu * a;
    }
    bf8_t Bf[2];
#pragma unroll
    for (int mg = 0; mg < 2; ++mg) {
      const unsigned short* p = B00[mg] + kc;
      bf8_t s00 = *(const bf8_t*)p;
      bf8_t s01 = *(const bf8_t*)(p + 256);
      bf8_t s10 = *(const bf8_t*)(p + 64 * 256);
      bf8_t s11 = *(const bf8_t*)(p + 65 * 256);
      Bf[mg] = pool_affine(s00, s01, s10, s11, a4, b8);
    }
    bf8_t A[2];
#pragma unroll
    for (int og = 0; og < 2; ++og) A[og] = *(const bf8_t*)(Abase + (size_t)og * 16 * 256 + kc);
#pragma unroll
    for (int og = 0; og < 2; ++og)
#pragma unroll
      for (int mg = 0; mg < 2; ++mg)
        acc[og][mg] = __builtin_amdgcn_mfma_f32_16x16x32_bf16(A[og], Bf[mg], acc[og][mg], 0, 0, 0);
  }
  if (w < 2) {
#pragma unroll
    for (int og = 0; og < 2; ++og)
#pragma unroll
      for (int mg = 0; mg < 2; ++mg) {
        uint2 p;
        p.x = pk_rnd(acc[og][mg][0], acc[og][mg][1]);
        p.y = pk_rnd(acc[og][mg][2], acc[og][mg][3]);
        *(uint2*)&kv0[mg * 16 + lane16][wh * 32 + og * 16 + quad * 4] = p;
      }
  } else {
#pragma unroll
    for (int og = 0; og < 2; ++og)
#pragma unroll
      for (int mg = 0; mg < 2; ++mg) {
        const int d0 = wh * 32 + og * 16 + quad * 4;
#pragma unroll
        for (int r = 0; r < 4; ++r)
          kv1[d0 + r][mg * 16 + lane16] = f2bf(acc[og][mg][r]);
      }
  }
  __syncthreads();
  {
    const int rowk = t >> 3, ch = t & 7, e = rowk & 7;
    *(uint4*)(kbf + (size_t)b * 65536 + (size_t)(m0 + rowk) * 64 + ((ch ^ e) * 8)) =
        *(const uint4*)&kv0[rowk][ch * 8];
    const int rowd = t >> 2, q = t & 3;
    *(uint4*)(vtbf + (size_t)b * 65536 + (size_t)(m0 >> 5) * 2048 + (size_t)rowd * 32 + q * 8) =
        *(const uint4*)&kv1[rowd][q * 8];
  }
}

__global__ __launch_bounds__(256) void k_fused(const unsigned short* __restrict__ wqb,
                                               const unsigned short* __restrict__ xtb,
                                               const float* __restrict__ gnw,
                                               const float* __restrict__ gnb,
                                               const float* __restrict__ stats,
                                               const unsigned short* __restrict__ kbf,
                                               const unsigned short* __restrict__ vtbf,
                                               const unsigned short* __restrict__ wob,
                                               const float* __restrict__ x,
                                               const float* __restrict__ gamma,
                                               float* __restrict__ outp) {
  __shared__ __align__(16) unsigned short smem[20480];
  __shared__ __align__(16) unsigned short kst[2][2048];
  __shared__ __align__(16) unsigned short vst[2][2048];
  const int t = threadIdx.x;
  const int w = t >> 6, l = t & 63, lane16 = l & 15, quad = l >> 4;
  const int n0 = blockIdx.x * 64, b = blockIdx.y;
  const int h = w;
  unsigned short* qst = smem + w * 4608;
  unsigned short (*plds)[64][40] = (unsigned short (*)[64][40])(smem + w * 5120);
  unsigned short (*aos)[264] = (unsigned short (*)[264])smem;
  const float mu = stats[b * 2 + 0] * CNT_INV;
  const float rstd = rsqrtf(stats[b * 2 + 1] * CNT_INV - mu * mu + EPSV);
  const int sw = w & 1;
  const unsigned short* sbase = (w < 2) ? (kbf + (size_t)b * 65536) : (vtbf + (size_t)b * 65536);
  unsigned short* sdst0 = ((w < 2) ? &kst[0][0] : &vst[0][0]) + sw * 1024 + l * 8;
  unsigned short* sdst1 = ((w < 2) ? &kst[1][0] : &vst[1][0]) + sw * 1024 + l * 8;

#define STAGE_ISSUE(WIN, R0, R1)                                              \
  { const unsigned short* sp = sbase + (size_t)(WIN) * 2048 + sw * 1024 + l * 8; \
    R0 = *(const uint4*)sp; R1 = *(const uint4*)(sp + 512); }
#define STAGE_WRITE(DP, R0, R1)                                               \
  { *(uint4*)(DP) = R0; *(uint4*)((DP) + 512) = R1; }
#define READ_K(BUF, KREG)                                                     \
  {                                                                           \
    _Pragma("unroll")                                                         \
    for (int s = 0; s < 2; ++s) {                                             \
      _Pragma("unroll")                                                       \
      for (int dc = 0; dc < 2; ++dc)                                          \
        KREG[s][dc] = *(const bf8_t*)&kst[BUF][(s * 16 + lane16) * 64 +       \
                                              (((dc * 4 + quad) ^ (lane16 & 7)) * 8)]; \
    }                                                                         \
  }
#define READ_V(BUF, VREG)                                                     \
  {                                                                           \
    _Pragma("unroll")                                                         \
    for (int dg = 0; dg < 4; ++dg)                                            \
      VREG[dg] = *(const bf8_t*)&vst[BUF][(dg * 16 + lane16) * 32 + quad * 8]; \
  }
#define SSTEP(KREG, BUF)                                                      \
  {                                                                           \
    _Pragma("unroll")                                                         \
    for (int qg = 0; qg < 4; ++qg) {                                          \
      _Pragma("unroll")                                                       \
      for (int s = 0; s < 2; ++s) {                                           \
        f4_t S = (f4_t){0.f, 0.f, 0.f, 0.f};                                  \
        S = __builtin_amdgcn_mfma_f32_16x16x32_bf16(KREG[s][0], Qf[qg][0], S, 0, 0, 0); \
        S = __builtin_amdgcn_mfma_f32_16x16x32_bf16(KREG[s][1], Qf[qg][1], S, 0, 0, 0); \
        float e0 = fexp2(S[0]);                                               \
        float e1 = fexp2(S[1]);                                               \
        float e2 = fexp2(S[2]);                                               \
        float e3 = fexp2(S[3]);                                               \
        uint2 p; p.x = pk_tr(e0, e1); p.y = pk_tr(e2, e3);                    \
        *(uint2*)&plds[BUF][qg * 16 + lane16][s * 16 + quad * 4] = p;         \
      }                                                                       \
    }                                                                         \
  }

  {
    const unsigned short* Abase = wqb + (size_t)(h * 64 + lane16) * 256 + quad * 8;
    const unsigned short* Bbase = xtb + ((size_t)b * 4096 + n0 + lane16) * 256 + quad * 8;
    f4_t qacc[4][4];
#pragma unroll
    for (int i = 0; i < 4; ++i)
#pragma unroll
      for (int j = 0; j < 4; ++j) qacc[i][j] = (f4_t){0.f, 0.f, 0.f, 0.f};
    for (int kc = 0; kc < 256; kc += 32) {
      const int cb = kc + quad * 8;
      float4 g0 = *(const float4*)&gnw[cb];
      float4 g1 = *(const float4*)&gnw[cb + 4];
      float4 h0 = *(const float4*)&gnb[cb];
      float4 h1 = *(const float4*)&gnb[cb + 4];
      float a8[8], b8[8];
      const float gg[8] = {g0.x, g0.y, g0.z, g0.w, g1.x, g1.y, g1.z, g1.w};
      const float hh[8] = {h0.x, h0.y, h0.z, h0.w, h1.x, h1.y, h1.z, h1.w};
#pragma unroll
      for (int j = 0; j < 8; ++j) {
        a8[j] = gg[j] * rstd;
        b8[j] = hh[j] - mu * a8[j];
      }
      bf8_t A[4], Bf[4];
#pragma unroll
      for (int og = 0; og < 4; ++og) A[og] = *(const bf8_t*)(Abase + (size_t)og * 16 * 256 + kc);
#pragma unroll
      for (int ng = 0; ng < 4; ++ng) {
        bf8_t raw = *(const bf8_t*)(Bbase + (size_t)ng * 16 * 256 + kc);
        Bf[ng] = affine8(raw, a8, b8);
      }
#pragma unroll
      for (int og = 0; og < 4; ++og)
#pragma unroll
        for (int ng = 0; ng < 4; ++ng)
          qacc[og][ng] = __builtin_amdgcn_mfma_f32_16x16x32_bf16(A[og], Bf[ng], qacc[og][ng], 0, 0, 0);
    }
#pragma unroll
    for (int og = 0; og < 4; ++og)
#pragma unroll
      for (int ng = 0; ng < 4; ++ng) {
        uint2 p;
        p.x = pk_rnd(qacc[og][ng][0] * QSCALE, qacc[og][ng][1] * QSCALE);
        p.y = pk_rnd(qacc[og][ng][2] * QSCALE, qacc[og][ng][3] * QSCALE);
        *(uint2*)&qst[(ng * 16 + lane16) * 72 + og * 16 + quad * 4] = p;
      }
  }
  bf8_t Qf[4][2];
#pragma unroll
  for (int qg = 0; qg < 4; ++qg)
#pragma unroll
    for (int dc = 0; dc < 2; ++dc)
      Qf[qg][dc] = *(const bf8_t*)&qst[(qg * 16 + lane16) * 72 + dc * 32 + quad * 8];
  __syncthreads();

  f4_t O[4][4];
#pragma unroll
  for (int dg = 0; dg < 4; ++dg)
#pragma unroll
    for (int qg = 0; qg < 4; ++qg) O[dg][qg] = (f4_t){0.f, 0.f, 0.f, 0.f};
  f4_t O4[4];
#pragma unroll
  for (int qg = 0; qg < 4; ++qg) O4[qg] = (f4_t){0.f, 0.f, 0.f, 0.f};
  const short onebf = (lane16 == 0) ? (short)0x3F80 : (short)0;
  const bf8_t Aone = {onebf, onebf, onebf, onebf, onebf, onebf, onebf, onebf};

  {
    uint4 a0, a1, b0, b1;
    STAGE_ISSUE(0, a0, a1);
    STAGE_ISSUE(1, b0, b1);
    STAGE_WRITE(sdst0, a0, a1);
    STAGE_WRITE(sdst1, b0, b1);
  }
  __syncthreads();

  bf8_t Kc[2][2], Vc[4];
  READ_K(0, Kc);
  SSTEP(Kc, 0);
  READ_V(0, Vc);
  __syncthreads();

  for (int it = 1; it < 32; ++it) {
    const int cur = it & 1, pb = cur ^ 1;
    uint4 g0, g1;
    if (it < 31) STAGE_ISSUE(it + 1, g0, g1);
    bf8_t Pf[4];
#pragma unroll
    for (int qg = 0; qg < 4; ++qg)
      Pf[qg] = *(const bf8_t*)&plds[pb][qg * 16 + lane16][quad * 8];
    READ_K(cur, Kc);
    bf8_t Vn[4];
    READ_V(cur, Vn);
    __builtin_amdgcn_s_setprio(1);
#pragma unroll
    for (int dg = 0; dg < 4; ++dg)
#pragma unroll
      for (int qg = 0; qg < 4; ++qg)
        O[dg][qg] = __builtin_amdgcn_mfma_f32_16x16x32_bf16(Vc[dg], Pf[qg], O[dg][qg], 0, 0, 0);
#pragma unroll
    for (int qg = 0; qg < 4; ++qg)
      O4[qg] = __builtin_amdgcn_mfma_f32_16x16x32_bf16(Aone, Pf[qg], O4[qg], 0, 0, 0);
    __builtin_amdgcn_s_setprio(0);
    SSTEP(Kc, cur);
#pragma unroll
    for (int dg = 0; dg < 4; ++dg) Vc[dg] = Vn[dg];
    if (it < 31) STAGE_WRITE((cur ? sdst0 : sdst1), g0, g1);
    __syncthreads();
  }
  {
    bf8_t Pf[4];
#pragma unroll
    for (int qg = 0; qg < 4; ++qg)
      Pf[qg] = *(const bf8_t*)&plds[1][qg * 16 + lane16][quad * 8];
    __builtin_amdgcn_s_setprio(1);
#pragma unroll
    for (int dg = 0; dg < 4; ++dg)
#pragma unroll
      for (int qg = 0; qg < 4; ++qg)
        O[dg][qg] = __builtin_amdgcn_mfma_f32_16x16x32_bf16(Vc[dg], Pf[qg], O[dg][qg], 0, 0, 0);
#pragma unroll
    for (int qg = 0; qg < 4; ++qg)
      O4[qg] = __builtin_amdgcn_mfma_f32_16x16x32_bf16(Aone, Pf[qg], O4[qg], 0, 0, 0);
    __builtin_amdgcn_s_setprio(0);
  }
#undef SSTEP
#undef STAGE_ISSUE
#undef STAGE_WRITE
#undef READ_K
#undef READ_V

  float rden[4];
#pragma unroll
  for (int qg = 0; qg < 4; ++qg) {
    float d = __shfl(O4[qg][0], lane16);
    rden[qg] = 1.f / d;
  }

  __syncthreads();
#pragma unroll
  for (int dg = 0; dg < 4; ++dg)
#pragma unroll
    for (int qg = 0; qg < 4; ++qg) {
      const int c0 = h * 64 + dg * 16 + quad * 4;
      uint2 p;
      p.x = pk_rnd(O[dg][qg][0] * rden[qg], O[dg][qg][1] * rden[qg]);
      p.y = pk_rnd(O[dg][qg][2] * rden[qg], O[dg][qg][3] * rden[qg]);
      *(uint2*)&aos[qg * 16 + lane16][c0] = p;
    }
  __syncthreads();

  {
    const unsigned short* Wbase = wob + (size_t)(w * 64 + lane16) * 256 + quad * 8;
    f4_t acc[4][4];
#pragma unroll
    for (int i = 0; i < 4; ++i)
#pragma unroll
      for (int j = 0; j < 4; ++j) acc[i][j] = (f4_t){0.f, 0.f, 0.f, 0.f};
    for (int kc = 0; kc < 256; kc += 32) {
      bf8_t A[4], Bf[4];
#pragma unroll
      for (int og = 0; og < 4; ++og) A[og] = *(const bf8_t*)(Wbase + (size_t)og * 16 * 256 + kc);
#pragma unroll
      for (int ng = 0; ng < 4; ++ng) Bf[ng] = *(const bf8_t*)&aos[ng * 16 + lane16][kc + quad * 8];
#pragma unroll
      for (int og = 0; og < 4; ++og)
#pragma unroll
        for (int ng = 0; ng < 4; ++ng)
          acc[og][ng] = __builtin_amdgcn_mfma_f32_16x16x32_bf16(A[og], Bf[ng], acc[og][ng], 0, 0, 0);
    }
#pragma unroll
    for (int og = 0; og < 4; ++og) {
      float4 g4 = *(const float4*)&gamma[w * 64 + og * 16 + quad * 4];
      const float g[4] = {g4.x, g4.y, g4.z, g4.w};
#pragma unroll
      for (int ng = 0; ng < 4; ++ng) {
        const int n = n0 + ng * 16 + lane16;
#pragma unroll
        for (int r = 0; r < 4; ++r) {
          const int o = w * 64 + og * 16 + quad * 4 + r;
          const size_t ix = ((size_t)(b * 256 + o)) * 4096 + n;
          outp[ix] = x[ix] + g[r] * acc[og][ng][r];
        }
      }
    }
  }
}

extern "C" void kernel_launch(void* const* d_in, const int* in_sizes, int n_in,
                              void* d_out, int out_size, void* d_ws, size_t ws_size,
                              hipStream_t stream) {
  const float* x     = (const float*)d_in[0];
  const float* gnw   = (const float*)d_in[1];
  const float* gnb   = (const float*)d_in[2];
  const float* wq    = (const float*)d_in[3];
  const float* wk    = (const float*)d_in[4];
  const float* wv    = (const float*)d_in[5];
  const float* wo    = (const float*)d_in[6];
  const float* gamma = (const float*)d_in[7];
  float* out = (float*)d_out;
  float* ws  = (float*)d_ws;
  float* statsp = ws + WS_STATS;
  unsigned short* xtb  = (unsigned short*)(ws + WS_XNT);
  unsigned short* kbf  = (unsigned short*)(ws + WS_K);
  unsigned short* vtbf = (unsigned short*)(ws + WS_V);
  unsigned short* wqb  = (unsigned short*)(ws + WS_WQB);
  unsigned short* wkvb = (unsigned short*)(ws + WS_WKV);
  unsigned short* wob  = (unsigned short*)(ws + WS_WOB);

  hipMemsetAsync(ws, 0, 256, stream);
  void* args[] = {(void*)&x, (void*)&gnw, (void*)&gnb, (void*)&wq, (void*)&wk, (void*)&wv,
                  (void*)&wo, (void*)&gamma, (void*)&statsp, (void*)&wqb, (void*)&wkvb,
                  (void*)&wob, (void*)&xtb, (void*)&kbf, (void*)&vtbf, (void*)&out};
  hipError_t err = hipLaunchCooperativeKernel((void*)k_all, dim3(512), dim3(256),
                                              args, 0, stream);
  if (err != hipSuccess) {
    // fallback: R13 3-kernel path
    k_prep<<<2176, 256, 0, stream>>>(x, wq, wk, wv, wo, statsp, wqb, wkvb, wob, xtb);
    k_gemm_kv<<<dim3(32, 8), 256, 0, stream>>>(wkvb, xtb, gnw, gnb, statsp, kbf, vtbf);
    k_fused<<<dim3(64, 8), 256, 0, stream>>>(wqb, xtb, gnw, gnb, statsp, kbf, vtbf, wob,
                                             x, gamma, out);
  }
}

// Round 9
// 193.814 us; speedup vs baseline: 2.2793x; 2.2793x over previous
//
#include <hip/hip_runtime.h>
#include <hip/hip_cooperative_groups.h>

namespace cg = cooperative_groups;

// MobileMQA: B=8, C=256, H=W=64, NUM_HEADS=4, hd=64, ds=2
// R16: two occupancy-matched cooperative kernels (R15 design) with hazards
//      removed: k_prep_c now 512 blocks (2 tiles/block, 36.9KB LDS), coop
//      viability decided by capture-safe occupancy QUERY (no error-branching
//      on launches during graph capture), k_att grid flattened to 1D 512.
//      Fallback = proven R12 4-kernel chain (194us).

#define CNT_INV (1.0f/1048576.0f)
#define EPSV 1e-5f
#define QSCALE 0.18033688f   // 0.125 * log2(e): folded into Q; exp = v_exp_f32(S)

// workspace layout (float offsets) — R12 layout
#define WS_STATS 0                    // 64
#define WS_XNT   64                   // bf16 xnT [b][n][c]  = 4,194,304 f
#define WS_XDS   4194368              // bf16 xdsT [b][m][c] = 1,048,576 f
#define WS_K     5242944              // bf16 k   [b][m][d]  = 262,144 f
#define WS_V     5505088              // bf16 v windows      = 262,144 f
#define WS_WQB   5767232              // bf16 wq  [o][c]     = 32,768 f
#define WS_WKV   5800000              // bf16 [wk;wv]        = 16,384 f
#define WS_WOB   5816384              // bf16 wo  [o][c]     = 32,768 f

typedef __attribute__((ext_vector_type(8))) short bf8_t;   // 8 bf16 MFMA A/B frag
typedef __attribute__((ext_vector_type(4))) float f4_t;    // MFMA C/D frag

static __device__ __forceinline__ unsigned fbits(float f) {
  union { float f; unsigned u; } v; v.f = f; return v.u;
}
static __device__ __forceinline__ unsigned short f2bf(float f) {  // RNE-ish
  unsigned u = fbits(f);
  return (unsigned short)((u + 0x7fffu + ((u >> 16) & 1u)) >> 16);
}
static __device__ __forceinline__ unsigned pk_rnd(float a, float b) {
  return __builtin_amdgcn_perm(fbits(b) + 0x8000u, fbits(a) + 0x8000u, 0x07060302u);
}
static __device__ __forceinline__ unsigned pk_tr(float a, float b) {
  return __builtin_amdgcn_perm(fbits(b), fbits(a), 0x07060302u);
}
static __device__ __forceinline__ float bf2f(unsigned short h) {
  union { unsigned u; float f; } v; v.u = ((unsigned)h) << 16; return v.f;
}
static __device__ __forceinline__ float fexp2(float x) {   // 2^x, raw v_exp_f32
  float r; asm("v_exp_f32 %0, %1" : "=v"(r) : "v"(x)); return r;
}

// ==================== k_prep_c: cooperative prep (512 blocks) ====================
// bid = b*64 + pair; each block handles tiles pair*2, pair*2+1 (tile: cq=tile>>5, hp=tile&31)
__global__ __launch_bounds__(256) void k_prep_c(const float* __restrict__ x,
                                                const float* __restrict__ gnw,
                                                const float* __restrict__ gnb,
                                                const float* __restrict__ wq,
                                                const float* __restrict__ wk,
                                                const float* __restrict__ wv,
                                                const float* __restrict__ wo,
                                                unsigned short* __restrict__ wqb,
                                                unsigned short* __restrict__ wkvb,
                                                unsigned short* __restrict__ wob,
                                                unsigned short* __restrict__ xnT,
                                                unsigned short* __restrict__ xdsT,
                                                float* __restrict__ partials) {
  __shared__ unsigned short T[2][128][72];   // raw bf16 tiles, chunk-swizzled
  __shared__ float red[8];
  cg::grid_group grid = cg::this_grid();
  const int t = threadIdx.x;
  const int bid = blockIdx.x;            // 0..511
  const int b = bid >> 6, pair = bid & 63;

  // ---- phase 1: both tiles -> LDS (raw bf16) + stats partials + weights ----
  float s = 0.f, s2 = 0.f;
  const int n4 = (t & 31) * 4, cl = t >> 5;
  const int wswz = t & 7;                // (row>>2)&7 for rows n4..n4+3
#pragma unroll
  for (int sub = 0; sub < 2; ++sub) {
    const int tile = pair * 2 + sub;
    const int c0 = (tile >> 5) * 64, n0 = (tile & 31) * 128;
#pragma unroll
    for (int p = 0; p < 8; ++p) {
      const int c = c0 + p * 8 + cl;
      const int pc = (p ^ wswz) * 8 + cl;
      float4 v = *(const float4*)&x[(size_t)(b * 256 + c) * 4096 + n0 + n4];
      s  += (v.x + v.y) + (v.z + v.w);
      s2 += (v.x * v.x + v.y * v.y) + (v.z * v.z + v.w * v.w);
      T[sub][n4 + 0][pc] = f2bf(v.x);
      T[sub][n4 + 1][pc] = f2bf(v.y);
      T[sub][n4 + 2][pc] = f2bf(v.z);
      T[sub][n4 + 3][pc] = f2bf(v.w);
    }
  }
  for (int k2 = t; k2 < 320; k2 += 256) {   // 512 blocks x 320 = 163,840 weights
    const int idx = bid * 320 + k2;
    if (idx < 65536) wqb[idx] = f2bf(wq[idx]);
    else if (idx < 81920) wkvb[idx - 65536] = f2bf(wk[idx - 65536]);
    else if (idx < 98304) wkvb[idx - 65536] = f2bf(wv[idx - 81920]);
    else wob[idx - 98304] = f2bf(wo[idx - 98304]);
  }
#pragma unroll
  for (int o = 32; o > 0; o >>= 1) {
    s  += __shfl_down(s, o);
    s2 += __shfl_down(s2, o);
  }
  if ((t & 63) == 0) { red[t >> 6] = s; red[4 + (t >> 6)] = s2; }
  __syncthreads();
  if (t == 0) {
    partials[bid * 2 + 0] = red[0] + red[1] + red[2] + red[3];
    partials[bid * 2 + 1] = red[4] + red[5] + red[6] + red[7];
  }
  __threadfence();
  grid.sync();

  // ---- phase 2: reduce this batch's 64 partials (every wave, redundantly) ----
  float ps = partials[((size_t)b * 64 + (t & 63)) * 2 + 0];
  float p2 = partials[((size_t)b * 64 + (t & 63)) * 2 + 1];
#pragma unroll
  for (int o = 32; o > 0; o >>= 1) {
    ps += __shfl_down(ps, o);
    p2 += __shfl_down(p2, o);
  }
  ps = __shfl(ps, 0);
  p2 = __shfl(p2, 0);
  const float mu = ps * CNT_INV;
  const float rstd = rsqrtf(p2 * CNT_INV - mu * mu + EPSV);

  // ---- normalize-write xnT + pooled xdsT from LDS-resident tiles ----
#pragma unroll
  for (int sub = 0; sub < 2; ++sub) {
    const int tile = pair * 2 + sub;
    const int c0 = (tile >> 5) * 64, n0 = (tile & 31) * 128;
    {  // xnT: 128 rows x 64 c
      const int r = t >> 1, cb4 = (t & 1) * 4;
      const int rswz = (t >> 3) & 7;     // (r>>2)&7
      unsigned short* dst = xnT + ((size_t)b * 4096 + n0 + r) * 256 + c0 + cb4 * 8;
#pragma unroll
      for (int u = 0; u < 4; ++u) {
        const int lc = cb4 + u;
        union { uint4 q; unsigned short us[8]; } raw;
        raw.q = *(const uint4*)&T[sub][r][(lc ^ rswz) * 8];
        const int cb = c0 + lc * 8;
        float4 g0 = *(const float4*)&gnw[cb];
        float4 g1 = *(const float4*)&gnw[cb + 4];
        float4 h0 = *(const float4*)&gnb[cb];
        float4 h1 = *(const float4*)&gnb[cb + 4];
        const float ga[8] = {g0.x, g0.y, g0.z, g0.w, g1.x, g1.y, g1.z, g1.w};
        const float ha[8] = {h0.x, h0.y, h0.z, h0.w, h1.x, h1.y, h1.z, h1.w};
        unsigned outw[4];
#pragma unroll
        for (int i = 0; i < 4; ++i) {
          const float a0 = ga[2 * i] * rstd,     b0 = ha[2 * i]     - mu * a0;
          const float a1 = ga[2 * i + 1] * rstd, b1 = ha[2 * i + 1] - mu * a1;
          outw[i] = pk_rnd(fmaf(bf2f(raw.us[2 * i]), a0, b0),
                           fmaf(bf2f(raw.us[2 * i + 1]), a1, b1));
        }
        *(uint4*)(dst + u * 8) = *(uint4*)outw;
      }
    }
    {  // pooled xdsT: 32 m x 64 c (affine after average, by linearity)
      const int wd = t >> 3, c8 = t & 7;
      const int pswz = (wd >> 1) & 7;
      const int pc = (c8 ^ pswz) * 8;
      union { uint4 q; unsigned short us[8]; } u0, u1, u2, u3;
      u0.q = *(const uint4*)&T[sub][2 * wd][pc];
      u1.q = *(const uint4*)&T[sub][2 * wd + 1][pc];
      u2.q = *(const uint4*)&T[sub][64 + 2 * wd][pc];
      u3.q = *(const uint4*)&T[sub][64 + 2 * wd + 1][pc];
      const int cb = c0 + c8 * 8;
      float4 g0 = *(const float4*)&gnw[cb];
      float4 g1 = *(const float4*)&gnw[cb + 4];
      float4 h0 = *(const float4*)&gnb[cb];
      float4 h1 = *(const float4*)&gnb[cb + 4];
      const float ga[8] = {g0.x, g0.y, g0.z, g0.w, g1.x, g1.y, g1.z, g1.w};
      const float ha[8] = {h0.x, h0.y, h0.z, h0.w, h1.x, h1.y, h1.z, h1.w};
      unsigned outw[4];
#pragma unroll
      for (int i = 0; i < 4; ++i) {
        const float a0 = ga[2 * i] * rstd;
        const float b0 = ha[2 * i] - mu * a0;
        const float a1 = ga[2 * i + 1] * rstd;
        const float b1 = ha[2 * i + 1] - mu * a1;
        float lo = (bf2f(u0.us[2 * i]) + bf2f(u1.us[2 * i])) +
                   (bf2f(u2.us[2 * i]) + bf2f(u3.us[2 * i]));
        float hi = (bf2f(u0.us[2 * i + 1]) + bf2f(u1.us[2 * i + 1])) +
                   (bf2f(u2.us[2 * i + 1]) + bf2f(u3.us[2 * i + 1]));
        outw[i] = pk_rnd(fmaf(lo, a0 * 0.25f, b0), fmaf(hi, a1 * 0.25f, b1));
      }
      *(uint4*)(xdsT + ((size_t)b * 1024 + (tile & 31) * 32 + wd) * 256 + cb) = *(uint4*)outw;
    }
  }
}

// ==================== k_att: cooperative KV gemm + Q-proj + attention (512 blocks 1D) ====================
__global__ __launch_bounds__(256) void k_att(const unsigned short* __restrict__ wqb,
                                             const unsigned short* __restrict__ wkvb,
                                             const unsigned short* __restrict__ xnT,
                                             const unsigned short* __restrict__ xdsT,
                                             const unsigned short* __restrict__ wob,
                                             unsigned short* __restrict__ kbf,
                                             unsigned short* __restrict__ vtbf,
                                             const float* __restrict__ x,
                                             const float* __restrict__ gamma,
                                             float* __restrict__ outp) {
  __shared__ __align__(16) unsigned short smem[20480];   // 40,960 B
  __shared__ __align__(16) unsigned short kst[2][2048];  //  8,192 B
  __shared__ __align__(16) unsigned short vst[2][2048];  //  8,192 B
  cg::grid_group grid = cg::this_grid();
  const int t = threadIdx.x;
  const int bid = blockIdx.x;            // 0..511
  const int b = bid >> 6, nt = bid & 63;
  const int w = t >> 6, l = t & 63, lane16 = l & 15, quad = l >> 4;
  const int n0 = nt * 64;
  const int h = w;
  unsigned short* qst = smem + w * 4608;                               // [64][72]
  unsigned short (*plds)[64][40] = (unsigned short (*)[64][40])(smem + w * 5120);
  unsigned short (*aos)[264] = (unsigned short (*)[264])smem;

  // ---- KV gemm: 16-m tile per block (aliased into kst/vst before staging use) ----
  {
    unsigned short (*kv0)[72] = (unsigned short (*)[72])(&kst[0][0]);  // [16][72] K
    unsigned short (*kv1)[24] = (unsigned short (*)[24])(&vst[0][0]);  // [64][24] V
    const int m0 = nt * 16;
    const int kvsel = w >> 1, wh = w & 1;
    const unsigned short* Abase = wkvb + (size_t)kvsel * 16384 +
                                  (size_t)(wh * 32 + lane16) * 256 + quad * 8;
    const unsigned short* Bbase = xdsT + ((size_t)b * 1024 + m0 + lane16) * 256 + quad * 8;
    f4_t acc0 = (f4_t){0.f, 0.f, 0.f, 0.f};
    f4_t acc1 = (f4_t){0.f, 0.f, 0.f, 0.f};
    for (int kc = 0; kc < 256; kc += 32) {
      bf8_t Bf = *(const bf8_t*)(Bbase + kc);
      bf8_t A0 = *(const bf8_t*)(Abase + kc);
      bf8_t A1 = *(const bf8_t*)(Abase + (size_t)16 * 256 + kc);
      acc0 = __builtin_amdgcn_mfma_f32_16x16x32_bf16(A0, Bf, acc0, 0, 0, 0);
      acc1 = __builtin_amdgcn_mfma_f32_16x16x32_bf16(A1, Bf, acc1, 0, 0, 0);
    }
    if (w < 2) {  // K rows d = wh*32 + og*16 + quad*4 + r, col m = lane16
      uint2 p0, p1;
      p0.x = pk_rnd(acc0[0], acc0[1]);
      p0.y = pk_rnd(acc0[2], acc0[3]);
      p1.x = pk_rnd(acc1[0], acc1[1]);
      p1.y = pk_rnd(acc1[2], acc1[3]);
      *(uint2*)&kv0[lane16][wh * 32 + quad * 4] = p0;
      *(uint2*)&kv0[lane16][wh * 32 + 16 + quad * 4] = p1;
    } else {      // V -> kv1[d][m]
#pragma unroll
      for (int r = 0; r < 4; ++r) {
        kv1[wh * 32 + quad * 4 + r][lane16] = f2bf(acc0[r]);
        kv1[wh * 32 + 16 + quad * 4 + r][lane16] = f2bf(acc1[r]);
      }
    }
    __syncthreads();
    if (t < 128) {  // coalesced writeout to R12 global layouts
      const int row = t >> 3, ch = t & 7, e = row & 7;  // (m0+row)&7 == row&7 (16|m0)
      *(uint4*)(kbf + (size_t)b * 65536 + (size_t)(m0 + row) * 64 + ((ch ^ e) * 8)) =
          *(const uint4*)&kv0[row][ch * 8];
      const int rowd = t >> 1, q = t & 1;
      *(uint4*)(vtbf + (size_t)b * 65536 + (size_t)(nt >> 1) * 2048 + (size_t)rowd * 32 +
                (nt & 1) * 16 + q * 8) = *(const uint4*)&kv1[rowd][q * 8];
    }
  }

  // ---- Q-proj: 64q x 64d per head-wave from xnT (qst is per-wave private) ----
  {
    const unsigned short* Abase = wqb + (size_t)(h * 64 + lane16) * 256 + quad * 8;
    const unsigned short* Bbase = xnT + ((size_t)b * 4096 + n0 + lane16) * 256 + quad * 8;
    f4_t qacc[4][4];
#pragma unroll
    for (int i = 0; i < 4; ++i)
#pragma unroll
      for (int j = 0; j < 4; ++j) qacc[i][j] = (f4_t){0.f, 0.f, 0.f, 0.f};
    for (int kc = 0; kc < 256; kc += 32) {
      bf8_t A[4], Bf[4];
#pragma unroll
      for (int og = 0; og < 4; ++og) A[og] = *(const bf8_t*)(Abase + (size_t)og * 16 * 256 + kc);
#pragma unroll
      for (int ng = 0; ng < 4; ++ng) Bf[ng] = *(const bf8_t*)(Bbase + (size_t)ng * 16 * 256 + kc);
#pragma unroll
      for (int og = 0; og < 4; ++og)
#pragma unroll
        for (int ng = 0; ng < 4; ++ng)
          qacc[og][ng] = __builtin_amdgcn_mfma_f32_16x16x32_bf16(A[og], Bf[ng], qacc[og][ng], 0, 0, 0);
    }
#pragma unroll
    for (int og = 0; og < 4; ++og)
#pragma unroll
      for (int ng = 0; ng < 4; ++ng) {
        uint2 p;
        p.x = pk_rnd(qacc[og][ng][0] * QSCALE, qacc[og][ng][1] * QSCALE);
        p.y = pk_rnd(qacc[og][ng][2] * QSCALE, qacc[og][ng][3] * QSCALE);
        *(uint2*)&qst[(ng * 16 + lane16) * 72 + og * 16 + quad * 4] = p;
      }
  }
  bf8_t Qf[4][2];
#pragma unroll
  for (int qg = 0; qg < 4; ++qg)
#pragma unroll
    for (int dc = 0; dc < 2; ++dc)
      Qf[qg][dc] = *(const bf8_t*)&qst[(qg * 16 + lane16) * 72 + dc * 32 + quad * 8];
  __threadfence();
  grid.sync();   // all K/V tiles globally visible; everyone's Q in regs

  // ---- attention + WO + residual (R12 verbatim) ----
  const int sw = w & 1;
  const unsigned short* sbase = (w < 2) ? (kbf + (size_t)b * 65536) : (vtbf + (size_t)b * 65536);
  unsigned short* sdst0 = ((w < 2) ? &kst[0][0] : &vst[0][0]) + sw * 1024 + l * 8;
  unsigned short* sdst1 = ((w < 2) ? &kst[1][0] : &vst[1][0]) + sw * 1024 + l * 8;

#define STAGE_ISSUE(WIN, R0, R1)                                              \
  { const unsigned short* sp = sbase + (size_t)(WIN) * 2048 + sw * 1024 + l * 8; \
    R0 = *(const uint4*)sp; R1 = *(const uint4*)(sp + 512); }
#define STAGE_WRITE(DP, R0, R1)                                               \
  { *(uint4*)(DP) = R0; *(uint4*)((DP) + 512) = R1; }
#define READ_K(BUF, KREG)                                                     \
  {                                                                           \
    _Pragma("unroll")                                                         \
    for (int s = 0; s < 2; ++s) {                                             \
      _Pragma("unroll")                                                       \
      for (int dc = 0; dc < 2; ++dc)                                          \
        KREG[s][dc] = *(const bf8_t*)&kst[BUF][(s * 16 + lane16) * 64 +       \
                                              (((dc * 4 + quad) ^ (lane16 & 7)) * 8)]; \
    }                                                                         \
  }
#define READ_V(BUF, VREG)                                                     \
  {                                                                           \
    _Pragma("unroll")                                                         \
    for (int dg = 0; dg < 4; ++dg)                                            \
      VREG[dg] = *(const bf8_t*)&vst[BUF][(dg * 16 + lane16) * 32 + quad * 8]; \
  }
#define SSTEP(KREG, BUF)                                                      \
  {                                                                           \
    _Pragma("unroll")                                                         \
    for (int qg = 0; qg < 4; ++qg) {                                          \
      _Pragma("unroll")                                                       \
      for (int s = 0; s < 2; ++s) {                                           \
        f4_t S = (f4_t){0.f, 0.f, 0.f, 0.f};                                  \
        S = __builtin_amdgcn_mfma_f32_16x16x32_bf16(KREG[s][0], Qf[qg][0], S, 0, 0, 0); \
        S = __builtin_amdgcn_mfma_f32_16x16x32_bf16(KREG[s][1], Qf[qg][1], S, 0, 0, 0); \
        float e0 = fexp2(S[0]);                                               \
        float e1 = fexp2(S[1]);                                               \
        float e2 = fexp2(S[2]);                                               \
        float e3 = fexp2(S[3]);                                               \
        uint2 p; p.x = pk_tr(e0, e1); p.y = pk_tr(e2, e3);                    \
        *(uint2*)&plds[BUF][qg * 16 + lane16][s * 16 + quad * 4] = p;         \
      }                                                                       \
    }                                                                         \
  }

  f4_t O[4][4];
#pragma unroll
  for (int dg = 0; dg < 4; ++dg)
#pragma unroll
    for (int qg = 0; qg < 4; ++qg) O[dg][qg] = (f4_t){0.f, 0.f, 0.f, 0.f};
  f4_t O4[4];
#pragma unroll
  for (int qg = 0; qg < 4; ++qg) O4[qg] = (f4_t){0.f, 0.f, 0.f, 0.f};
  const short onebf = (lane16 == 0) ? (short)0x3F80 : (short)0;
  const bf8_t Aone = {onebf, onebf, onebf, onebf, onebf, onebf, onebf, onebf};

  {  // prologue: stage windows 0 and 1
    uint4 a0, a1, b0, b1;
    STAGE_ISSUE(0, a0, a1);
    STAGE_ISSUE(1, b0, b1);
    STAGE_WRITE(sdst0, a0, a1);
    STAGE_WRITE(sdst1, b0, b1);
  }
  __syncthreads();

  bf8_t Kc[2][2], Vc[4];
  READ_K(0, Kc);
  SSTEP(Kc, 0);
  READ_V(0, Vc);
  __syncthreads();

  for (int it = 1; it < 32; ++it) {
    const int cur = it & 1, pb = cur ^ 1;
    uint4 g0, g1;
    if (it < 31) STAGE_ISSUE(it + 1, g0, g1);
    bf8_t Pf[4];
#pragma unroll
    for (int qg = 0; qg < 4; ++qg)
      Pf[qg] = *(const bf8_t*)&plds[pb][qg * 16 + lane16][quad * 8];
    READ_K(cur, Kc);
    bf8_t Vn[4];
    READ_V(cur, Vn);
    __builtin_amdgcn_s_setprio(1);
#pragma unroll
    for (int dg = 0; dg < 4; ++dg)
#pragma unroll
      for (int qg = 0; qg < 4; ++qg)
        O[dg][qg] = __builtin_amdgcn_mfma_f32_16x16x32_bf16(Vc[dg], Pf[qg], O[dg][qg], 0, 0, 0);
#pragma unroll
    for (int qg = 0; qg < 4; ++qg)
      O4[qg] = __builtin_amdgcn_mfma_f32_16x16x32_bf16(Aone, Pf[qg], O4[qg], 0, 0, 0);
    __builtin_amdgcn_s_setprio(0);
    SSTEP(Kc, cur);
#pragma unroll
    for (int dg = 0; dg < 4; ++dg) Vc[dg] = Vn[dg];
    if (it < 31) STAGE_WRITE((cur ? sdst0 : sdst1), g0, g1);
    __syncthreads();
  }
  {  // epilogue: PV(31), P in buf 1
    bf8_t Pf[4];
#pragma unroll
    for (int qg = 0; qg < 4; ++qg)
      Pf[qg] = *(const bf8_t*)&plds[1][qg * 16 + lane16][quad * 8];
    __builtin_amdgcn_s_setprio(1);
#pragma unroll
    for (int dg = 0; dg < 4; ++dg)
#pragma unroll
      for (int qg = 0; qg < 4; ++qg)
        O[dg][qg] = __builtin_amdgcn_mfma_f32_16x16x32_bf16(Vc[dg], Pf[qg], O[dg][qg], 0, 0, 0);
#pragma unroll
    for (int qg = 0; qg < 4; ++qg)
      O4[qg] = __builtin_amdgcn_mfma_f32_16x16x32_bf16(Aone, Pf[qg], O4[qg], 0, 0, 0);
    __builtin_amdgcn_s_setprio(0);
  }
#undef SSTEP
#undef STAGE_ISSUE
#undef STAGE_WRITE
#undef READ_K
#undef READ_V

  float rden[4];
#pragma unroll
  for (int qg = 0; qg < 4; ++qg) {
    float d = __shfl(O4[qg][0], lane16);
    rden[qg] = 1.f / d;
  }

  __syncthreads();
#pragma unroll
  for (int dg = 0; dg < 4; ++dg)
#pragma unroll
    for (int qg = 0; qg < 4; ++qg) {
      const int c0 = h * 64 + dg * 16 + quad * 4;
      uint2 p;
      p.x = pk_rnd(O[dg][qg][0] * rden[qg], O[dg][qg][1] * rden[qg]);
      p.y = pk_rnd(O[dg][qg][2] * rden[qg], O[dg][qg][3] * rden[qg]);
      *(uint2*)&aos[qg * 16 + lane16][c0] = p;
    }
  __syncthreads();

  {  // WO gemm from LDS + residual
    const unsigned short* Wbase = wob + (size_t)(w * 64 + lane16) * 256 + quad * 8;
    f4_t acc[4][4];
#pragma unroll
    for (int i = 0; i < 4; ++i)
#pragma unroll
      for (int j = 0; j < 4; ++j) acc[i][j] = (f4_t){0.f, 0.f, 0.f, 0.f};
    for (int kc = 0; kc < 256; kc += 32) {
      bf8_t A[4], Bf[4];
#pragma unroll
      for (int og = 0; og < 4; ++og) A[og] = *(const bf8_t*)(Wbase + (size_t)og * 16 * 256 + kc);
#pragma unroll
      for (int ng = 0; ng < 4; ++ng) Bf[ng] = *(const bf8_t*)&aos[ng * 16 + lane16][kc + quad * 8];
#pragma unroll
      for (int og = 0; og < 4; ++og)
#pragma unroll
        for (int ng = 0; ng < 4; ++ng)
          acc[og][ng] = __builtin_amdgcn_mfma_f32_16x16x32_bf16(A[og], Bf[ng], acc[og][ng], 0, 0, 0);
    }
#pragma unroll
    for (int og = 0; og < 4; ++og) {
      float4 g4 = *(const float4*)&gamma[w * 64 + og * 16 + quad * 4];
      const float g[4] = {g4.x, g4.y, g4.z, g4.w};
#pragma unroll
      for (int ng = 0; ng < 4; ++ng) {
        const int n = n0 + ng * 16 + lane16;
#pragma unroll
        for (int r = 0; r < 4; ++r) {
          const int o = w * 64 + og * 16 + quad * 4 + r;
          const size_t ix = ((size_t)(b * 256 + o)) * 4096 + n;
          outp[ix] = x[ix] + g[r] * acc[og][ng][r];
        }
      }
    }
  }
}

// ==================== R12 fallback kernels (proven) ====================
__global__ __launch_bounds__(256) void k_prep_stats(const float* __restrict__ x,
                                                    const float* __restrict__ wq,
                                                    const float* __restrict__ wk,
                                                    const float* __restrict__ wv,
                                                    const float* __restrict__ wo,
                                                    float* __restrict__ stats,
                                                    unsigned short* __restrict__ wqb,
                                                    unsigned short* __restrict__ wkvb,
                                                    unsigned short* __restrict__ wob) {
  const int blk = blockIdx.x;
  const int t = threadIdx.x;
  if (blk < 512) {
    const int b = blk >> 6;
    const int chunk = blk & 63;
    const float4* xb = (const float4*)(x + (size_t)b * 1048576 + (size_t)chunk * 16384);
    float s = 0.f, s2 = 0.f;
#pragma unroll
    for (int it = 0; it < 16; ++it) {
      float4 v = xb[it * 256 + t];
      s  += v.x + v.y + v.z + v.w;
      s2 += v.x * v.x + v.y * v.y + v.z * v.z + v.w * v.w;
    }
#pragma unroll
    for (int o = 32; o > 0; o >>= 1) {
      s  += __shfl_down(s, o);
      s2 += __shfl_down(s2, o);
    }
    __shared__ float red[8];
    const int wid = t >> 6;
    if ((t & 63) == 0) { red[wid] = s; red[4 + wid] = s2; }
    __syncthreads();
    if (t == 0) {
      atomicAdd(&stats[b * 2 + 0], red[0] + red[1] + red[2] + red[3]);
      atomicAdd(&stats[b * 2 + 1], red[4] + red[5] + red[6] + red[7]);
    }
  } else {
    const int idx = (blk - 512) * 256 + t;
    if (idx < 65536) wqb[idx] = f2bf(wq[idx]);
    else if (idx < 81920) wkvb[idx - 65536] = f2bf(wk[idx - 65536]);
    else if (idx < 98304) wkvb[idx - 65536] = f2bf(wv[idx - 81920]);
    else if (idx < 163840) wob[idx - 98304] = f2bf(wo[idx - 98304]);
  }
}

__global__ __launch_bounds__(256) void k_xnt(const float* __restrict__ x,
                                             const float* __restrict__ gnw,
                                             const float* __restrict__ gnb,
                                             const float* __restrict__ stats,
                                             unsigned short* __restrict__ xnT,
                                             unsigned short* __restrict__ xdsT) {
  __shared__ unsigned short T[128][72];
  const int t = threadIdx.x;
  const int b = blockIdx.z, c0 = blockIdx.y * 64, hp = blockIdx.x;
  const int n0 = hp * 128;
  const float mu = stats[b * 2 + 0] * CNT_INV;
  const float rstd = rsqrtf(stats[b * 2 + 1] * CNT_INV - mu * mu + EPSV);
  const int n4 = (t & 31) * 4, cl = t >> 5;
  const int wswz = t & 7;
#pragma unroll
  for (int p = 0; p < 8; ++p) {
    const int c = c0 + p * 8 + cl;
    const float gw = gnw[c] * rstd;
    const float gb = gnb[c] - mu * rstd * gnw[c];
    const int pc = (p ^ wswz) * 8 + cl;
    float4 v = *(const float4*)&x[(size_t)(b * 256 + c) * 4096 + n0 + n4];
    T[n4 + 0][pc] = f2bf(v.x * gw + gb);
    T[n4 + 1][pc] = f2bf(v.y * gw + gb);
    T[n4 + 2][pc] = f2bf(v.z * gw + gb);
    T[n4 + 3][pc] = f2bf(v.w * gw + gb);
  }
  __syncthreads();
  {
    const int r = t >> 1, cb4 = (t & 1) * 4;
    const int rswz = (t >> 3) & 7;
    unsigned short* dst = xnT + ((size_t)b * 4096 + n0 + r) * 256 + c0 + cb4 * 8;
#pragma unroll
    for (int u = 0; u < 4; ++u)
      *(uint4*)(dst + u * 8) = *(const uint4*)&T[r][((cb4 + u) ^ rswz) * 8];
  }
  {
    const int wd = t >> 3, c8 = t & 7;
    const int pswz = (wd >> 1) & 7;
    const int pc = (c8 ^ pswz) * 8;
    uint4 u0 = *(const uint4*)&T[2 * wd][pc];
    uint4 u1 = *(const uint4*)&T[2 * wd + 1][pc];
    uint4 u2 = *(const uint4*)&T[64 + 2 * wd][pc];
    uint4 u3 = *(const uint4*)&T[64 + 2 * wd + 1][pc];
    const unsigned* p0 = (const unsigned*)&u0; const unsigned* p1 = (const unsigned*)&u1;
    const unsigned* p2 = (const unsigned*)&u2; const unsigned* p3 = (const unsigned*)&u3;
    unsigned outv[4];
#pragma unroll
    for (int i = 0; i < 4; ++i) {
      float lo = (bf2f((unsigned short)p0[i]) + bf2f((unsigned short)p1[i]) +
                  bf2f((unsigned short)p2[i]) + bf2f((unsigned short)p3[i])) * 0.25f;
      float hi = (bf2f((unsigned short)(p0[i] >> 16)) + bf2f((unsigned short)(p1[i] >> 16)) +
                  bf2f((unsigned short)(p2[i] >> 16)) + bf2f((unsigned short)(p3[i] >> 16))) * 0.25f;
      outv[i] = pk_rnd(lo, hi);
    }
    *(uint4*)(xdsT + ((size_t)b * 1024 + hp * 32 + wd) * 256 + c0 + c8 * 8) = *(uint4*)outv;
  }
}

__global__ __launch_bounds__(256) void k_gemm_kv(const unsigned short* __restrict__ wkvb,
                                                 const unsigned short* __restrict__ xdsT,
                                                 unsigned short* __restrict__ kbf,
                                                 unsigned short* __restrict__ vtbf) {
  __shared__ __align__(16) unsigned short kv[2][64][72];
  const int t = threadIdx.x;
  const int w = t >> 6, l = t & 63, lane16 = l & 15, quad = l >> 4;
  const int m0 = blockIdx.x * 64, b = blockIdx.y;
  const unsigned short* Abase = wkvb + (size_t)(w * 32 + lane16) * 256 + quad * 8;
  const unsigned short* Bbase = xdsT + ((size_t)b * 1024 + m0 + lane16) * 256 + quad * 8;
  f4_t acc[2][4];
#pragma unroll
  for (int i = 0; i < 2; ++i)
#pragma unroll
    for (int j = 0; j < 4; ++j) acc[i][j] = (f4_t){0.f, 0.f, 0.f, 0.f};
  for (int kc = 0; kc < 256; kc += 32) {
    bf8_t A[2], Bf[4];
#pragma unroll
    for (int og = 0; og < 2; ++og) A[og] = *(const bf8_t*)(Abase + (size_t)og * 16 * 256 + kc);
#pragma unroll
    for (int mg = 0; mg < 4; ++mg) Bf[mg] = *(const bf8_t*)(Bbase + (size_t)mg * 16 * 256 + kc);
#pragma unroll
    for (int og = 0; og < 2; ++og)
#pragma unroll
      for (int mg = 0; mg < 4; ++mg)
        acc[og][mg] = __builtin_amdgcn_mfma_f32_16x16x32_bf16(A[og], Bf[mg], acc[og][mg], 0, 0, 0);
  }
  if (w < 2) {
#pragma unroll
    for (int og = 0; og < 2; ++og)
#pragma unroll
      for (int mg = 0; mg < 4; ++mg) {
        uint2 p;
        p.x = pk_rnd(acc[og][mg][0], acc[og][mg][1]);
        p.y = pk_rnd(acc[og][mg][2], acc[og][mg][3]);
        *(uint2*)&kv[0][mg * 16 + lane16][w * 32 + og * 16 + quad * 4] = p;
      }
  } else {
#pragma unroll
    for (int og = 0; og < 2; ++og)
#pragma unroll
      for (int mg = 0; mg < 4; ++mg) {
        const int d0 = (w - 2) * 32 + og * 16 + quad * 4;
#pragma unroll
        for (int r = 0; r < 4; ++r)
          kv[1][d0 + r][mg * 16 + lane16] = f2bf(acc[og][mg][r]);
      }
  }
  __syncthreads();
  {
    const int row = t >> 2, q2 = t & 3;
    const int e = row & 7;
    uint4 k0 = *(const uint4*)&kv[0][row][q2 * 16];
    uint4 k1 = *(const uint4*)&kv[0][row][q2 * 16 + 8];
    unsigned short* kd = kbf + (size_t)b * 65536 + (size_t)(m0 + row) * 64;
    *(uint4*)(kd + ((q2 * 2) ^ e) * 8)     = k0;
    *(uint4*)(kd + ((q2 * 2 + 1) ^ e) * 8) = k1;
    uint4 v0 = *(const uint4*)&kv[1][row][q2 * 16];
    uint4 v1 = *(const uint4*)&kv[1][row][q2 * 16 + 8];
    unsigned short* vd = vtbf + (size_t)b * 65536 + (size_t)(blockIdx.x * 2 + (q2 >> 1)) * 2048 +
                         (size_t)row * 32 + (q2 & 1) * 16;
    *(uint4*)vd = v0; *(uint4*)(vd + 8) = v1;
  }
}

__global__ __launch_bounds__(256) void k_fused(const unsigned short* __restrict__ wqb,
                                               const unsigned short* __restrict__ xnT,
                                               const unsigned short* __restrict__ kbf,
                                               const unsigned short* __restrict__ vtbf,
                                               const unsigned short* __restrict__ wob,
                                               const float* __restrict__ x,
                                               const float* __restrict__ gamma,
                                               float* __restrict__ outp) {
  __shared__ __align__(16) unsigned short smem[20480];
  __shared__ __align__(16) unsigned short kst[2][2048];
  __shared__ __align__(16) unsigned short vst[2][2048];
  const int t = threadIdx.x;
  const int w = t >> 6, l = t & 63, lane16 = l & 15, quad = l >> 4;
  const int n0 = blockIdx.x * 64, b = blockIdx.y;
  const int h = w;
  unsigned short* qst = smem + w * 4608;
  unsigned short (*plds)[64][40] = (unsigned short (*)[64][40])(smem + w * 5120);
  unsigned short (*aos)[264] = (unsigned short (*)[264])smem;
  const int sw = w & 1;
  const unsigned short* sbase = (w < 2) ? (kbf + (size_t)b * 65536) : (vtbf + (size_t)b * 65536);
  unsigned short* sdst0 = ((w < 2) ? &kst[0][0] : &vst[0][0]) + sw * 1024 + l * 8;
  unsigned short* sdst1 = ((w < 2) ? &kst[1][0] : &vst[1][0]) + sw * 1024 + l * 8;

#define STAGE_ISSUE(WIN, R0, R1)                                              \
  { const unsigned short* sp = sbase + (size_t)(WIN) * 2048 + sw * 1024 + l * 8; \
    R0 = *(const uint4*)sp; R1 = *(const uint4*)(sp + 512); }
#define STAGE_WRITE(DP, R0, R1)                                               \
  { *(uint4*)(DP) = R0; *(uint4*)((DP) + 512) = R1; }
#define READ_K(BUF, KREG)                                                     \
  {                                                                           \
    _Pragma("unroll")                                                         \
    for (int s = 0; s < 2; ++s) {                                             \
      _Pragma("unroll")                                                       \
      for (int dc = 0; dc < 2; ++dc)                                          \
        KREG[s][dc] = *(const bf8_t*)&kst[BUF][(s * 16 + lane16) * 64 +       \
                                              (((dc * 4 + quad) ^ (lane16 & 7)) * 8)]; \
    }                                                                         \
  }
#define READ_V(BUF, VREG)                                                     \
  {                                                                           \
    _Pragma("unroll")                                                         \
    for (int dg = 0; dg < 4; ++dg)                                            \
      VREG[dg] = *(const bf8_t*)&vst[BUF][(dg * 16 + lane16) * 32 + quad * 8]; \
  }
#define SSTEP(KREG, BUF)                                                      \
  {                                                                           \
    _Pragma("unroll")                                                         \
    for (int qg = 0; qg < 4; ++qg) {                                          \
      _Pragma("unroll")                                                       \
      for (int s = 0; s < 2; ++s) {                                           \
        f4_t S = (f4_t){0.f, 0.f, 0.f, 0.f};                                  \
        S = __builtin_amdgcn_mfma_f32_16x16x32_bf16(KREG[s][0], Qf[qg][0], S, 0, 0, 0); \
        S = __builtin_amdgcn_mfma_f32_16x16x32_bf16(KREG[s][1], Qf[qg][1], S, 0, 0, 0); \
        float e0 = fexp2(S[0]);                                               \
        float e1 = fexp2(S[1]);                                               \
        float e2 = fexp2(S[2]);                                               \
        float e3 = fexp2(S[3]);                                               \
        uint2 p; p.x = pk_tr(e0, e1); p.y = pk_tr(e2, e3);                    \
        *(uint2*)&plds[BUF][qg * 16 + lane16][s * 16 + quad * 4] = p;         \
      }                                                                       \
    }                                                                         \
  }

  {
    const unsigned short* Abase = wqb + (size_t)(h * 64 + lane16) * 256 + quad * 8;
    const unsigned short* Bbase = xnT + ((size_t)b * 4096 + n0 + lane16) * 256 + quad * 8;
    f4_t qacc[4][4];
#pragma unroll
    for (int i = 0; i < 4; ++i)
#pragma unroll
      for (int j = 0; j < 4; ++j) qacc[i][j] = (f4_t){0.f, 0.f, 0.f, 0.f};
    for (int kc = 0; kc < 256; kc += 32) {
      bf8_t A[4], Bf[4];
#pragma unroll
      for (int og = 0; og < 4; ++og) A[og] = *(const bf8_t*)(Abase + (size_t)og * 16 * 256 + kc);
#pragma unroll
      for (int ng = 0; ng < 4; ++ng) Bf[ng] = *(const bf8_t*)(Bbase + (size_t)ng * 16 * 256 + kc);
#pragma unroll
      for (int og = 0; og < 4; ++og)
#pragma unroll
        for (int ng = 0; ng < 4; ++ng)
          qacc[og][ng] = __builtin_amdgcn_mfma_f32_16x16x32_bf16(A[og], Bf[ng], qacc[og][ng], 0, 0, 0);
    }
#pragma unroll
    for (int og = 0; og < 4; ++og)
#pragma unroll
      for (int ng = 0; ng < 4; ++ng) {
        uint2 p;
        p.x = pk_rnd(qacc[og][ng][0] * QSCALE, qacc[og][ng][1] * QSCALE);
        p.y = pk_rnd(qacc[og][ng][2] * QSCALE, qacc[og][ng][3] * QSCALE);
        *(uint2*)&qst[(ng * 16 + lane16) * 72 + og * 16 + quad * 4] = p;
      }
  }
  bf8_t Qf[4][2];
#pragma unroll
  for (int qg = 0; qg < 4; ++qg)
#pragma unroll
    for (int dc = 0; dc < 2; ++dc)
      Qf[qg][dc] = *(const bf8_t*)&qst[(qg * 16 + lane16) * 72 + dc * 32 + quad * 8];
  __syncthreads();

  f4_t O[4][4];
#pragma unroll
  for (int dg = 0; dg < 4; ++dg)
#pragma unroll
    for (int qg = 0; qg < 4; ++qg) O[dg][qg] = (f4_t){0.f, 0.f, 0.f, 0.f};
  f4_t O4[4];
#pragma unroll
  for (int qg = 0; qg < 4; ++qg) O4[qg] = (f4_t){0.f, 0.f, 0.f, 0.f};
  const short onebf = (lane16 == 0) ? (short)0x3F80 : (short)0;
  const bf8_t Aone = {onebf, onebf, onebf, onebf, onebf, onebf, onebf, onebf};

  {
    uint4 a0, a1, b0, b1;
    STAGE_ISSUE(0, a0, a1);
    STAGE_ISSUE(1, b0, b1);
    STAGE_WRITE(sdst0, a0, a1);
    STAGE_WRITE(sdst1, b0, b1);
  }
  __syncthreads();

  bf8_t Kc[2][2], Vc[4];
  READ_K(0, Kc);
  SSTEP(Kc, 0);
  READ_V(0, Vc);
  __syncthreads();

  for (int it = 1; it < 32; ++it) {
    const int cur = it & 1, pb = cur ^ 1;
    uint4 g0, g1;
    if (it < 31) STAGE_ISSUE(it + 1, g0, g1);
    bf8_t Pf[4];
#pragma unroll
    for (int qg = 0; qg < 4; ++qg)
      Pf[qg] = *(const bf8_t*)&plds[pb][qg * 16 + lane16][quad * 8];
    READ_K(cur, Kc);
    bf8_t Vn[4];
    READ_V(cur, Vn);
    __builtin_amdgcn_s_setprio(1);
#pragma unroll
    for (int dg = 0; dg < 4; ++dg)
#pragma unroll
      for (int qg = 0; qg < 4; ++qg)
        O[dg][qg] = __builtin_amdgcn_mfma_f32_16x16x32_bf16(Vc[dg], Pf[qg], O[dg][qg], 0, 0, 0);
#pragma unroll
    for (int qg = 0; qg < 4; ++qg)
      O4[qg] = __builtin_amdgcn_mfma_f32_16x16x32_bf16(Aone, Pf[qg], O4[qg], 0, 0, 0);
    __builtin_amdgcn_s_setprio(0);
    SSTEP(Kc, cur);
#pragma unroll
    for (int dg = 0; dg < 4; ++dg) Vc[dg] = Vn[dg];
    if (it < 31) STAGE_WRITE((cur ? sdst0 : sdst1), g0, g1);
    __syncthreads();
  }
  {
    bf8_t Pf[4];
#pragma unroll
    for (int qg = 0; qg < 4; ++qg)
      Pf[qg] = *(const bf8_t*)&plds[1][qg * 16 + lane16][quad * 8];
    __builtin_amdgcn_s_setprio(1);
#pragma unroll
    for (int dg = 0; dg < 4; ++dg)
#pragma unroll
      for (int qg = 0; qg < 4; ++qg)
        O[dg][qg] = __builtin_amdgcn_mfma_f32_16x16x32_bf16(Vc[dg], Pf[qg], O[dg][qg], 0, 0, 0);
#pragma unroll
    for (int qg = 0; qg < 4; ++qg)
      O4[qg] = __builtin_amdgcn_mfma_f32_16x16x32_bf16(Aone, Pf[qg], O4[qg], 0, 0, 0);
    __builtin_amdgcn_s_setprio(0);
  }
#undef SSTEP
#undef STAGE_ISSUE
#undef STAGE_WRITE
#undef READ_K
#undef READ_V

  float rden[4];
#pragma unroll
  for (int qg = 0; qg < 4; ++qg) {
    float d = __shfl(O4[qg][0], lane16);
    rden[qg] = 1.f / d;
  }

  __syncthreads();
#pragma unroll
  for (int dg = 0; dg < 4; ++dg)
#pragma unroll
    for (int qg = 0; qg < 4; ++qg) {
      const int c0 = h * 64 + dg * 16 + quad * 4;
      uint2 p;
      p.x = pk_rnd(O[dg][qg][0] * rden[qg], O[dg][qg][1] * rden[qg]);
      p.y = pk_rnd(O[dg][qg][2] * rden[qg], O[dg][qg][3] * rden[qg]);
      *(uint2*)&aos[qg * 16 + lane16][c0] = p;
    }
  __syncthreads();

  {
    const unsigned short* Wbase = wob + (size_t)(w * 64 + lane16) * 256 + quad * 8;
    f4_t acc[4][4];
#pragma unroll
    for (int i = 0; i < 4; ++i)
#pragma unroll
      for (int j = 0; j < 4; ++j) acc[i][j] = (f4_t){0.f, 0.f, 0.f, 0.f};
    for (int kc = 0; kc < 256; kc += 32) {
      bf8_t A[4], Bf[4];
#pragma unroll
      for (int og = 0; og < 4; ++og) A[og] = *(const bf8_t*)(Wbase + (size_t)og * 16 * 256 + kc);
#pragma unroll
      for (int ng = 0; ng < 4; ++ng) Bf[ng] = *(const bf8_t*)&aos[ng * 16 + lane16][kc + quad * 8];
#pragma unroll
      for (int og = 0; og < 4; ++og)
#pragma unroll
        for (int ng = 0; ng < 4; ++ng)
          acc[og][ng] = __builtin_amdgcn_mfma_f32_16x16x32_bf16(A[og], Bf[ng], acc[og][ng], 0, 0, 0);
    }
#pragma unroll
    for (int og = 0; og < 4; ++og) {
      float4 g4 = *(const float4*)&gamma[w * 64 + og * 16 + quad * 4];
      const float g[4] = {g4.x, g4.y, g4.z, g4.w};
#pragma unroll
      for (int ng = 0; ng < 4; ++ng) {
        const int n = n0 + ng * 16 + lane16;
#pragma unroll
        for (int r = 0; r < 4; ++r) {
          const int o = w * 64 + og * 16 + quad * 4 + r;
          const size_t ix = ((size_t)(b * 256 + o)) * 4096 + n;
          outp[ix] = x[ix] + g[r] * acc[og][ng][r];
        }
      }
    }
  }
}

extern "C" void kernel_launch(void* const* d_in, const int* in_sizes, int n_in,
                              void* d_out, int out_size, void* d_ws, size_t ws_size,
                              hipStream_t stream) {
  const float* x     = (const float*)d_in[0];
  const float* gnw   = (const float*)d_in[1];
  const float* gnb   = (const float*)d_in[2];
  const float* wq    = (const float*)d_in[3];
  const float* wk    = (const float*)d_in[4];
  const float* wv    = (const float*)d_in[5];
  const float* wo    = (const float*)d_in[6];
  const float* gamma = (const float*)d_in[7];
  float* out = (float*)d_out;
  float* ws  = (float*)d_ws;
  float* statsp = ws + WS_STATS;
  unsigned short* xnT  = (unsigned short*)(ws + WS_XNT);
  unsigned short* xdsT = (unsigned short*)(ws + WS_XDS);
  unsigned short* kbf  = (unsigned short*)(ws + WS_K);
  unsigned short* vtbf = (unsigned short*)(ws + WS_V);
  unsigned short* wqb  = (unsigned short*)(ws + WS_WQB);
  unsigned short* wkvb = (unsigned short*)(ws + WS_WKV);
  unsigned short* wob  = (unsigned short*)(ws + WS_WOB);
  float* partials = (float*)(ws + WS_V);   // vtbf region is free until k_att writes it

  // capture-safe coop viability check (pure queries, no stream ops)
  int bpm1 = 0, bpm2 = 0;
  (void)hipOccupancyMaxActiveBlocksPerMultiprocessor(&bpm1, (const void*)k_prep_c, 256, 0);
  (void)hipOccupancyMaxActiveBlocksPerMultiprocessor(&bpm2, (const void*)k_att, 256, 0);

  if (bpm1 >= 2 && bpm2 >= 2) {   // 512 blocks on 256 CUs for both
    void* args1[] = {(void*)&x, (void*)&gnw, (void*)&gnb, (void*)&wq, (void*)&wk, (void*)&wv,
                     (void*)&wo, (void*)&wqb, (void*)&wkvb, (void*)&wob, (void*)&xnT,
                     (void*)&xdsT, (void*)&partials};
    hipLaunchCooperativeKernel((void*)k_prep_c, dim3(512), dim3(256), args1, 0, stream);
    void* args2[] = {(void*)&wqb, (void*)&wkvb, (void*)&xnT, (void*)&xdsT, (void*)&wob,
                     (void*)&kbf, (void*)&vtbf, (void*)&x, (void*)&gamma, (void*)&out};
    hipLaunchCooperativeKernel((void*)k_att, dim3(512), dim3(256), args2, 0, stream);
  } else {
    hipMemsetAsync(ws, 0, 256, stream);
    k_prep_stats<<<1152, 256, 0, stream>>>(x, wq, wk, wv, wo, statsp, wqb, wkvb, wob);
    k_xnt<<<dim3(32, 4, 8), 256, 0, stream>>>(x, gnw, gnb, statsp, xnT, xdsT);
    k_gemm_kv<<<dim3(16, 8), 256, 0, stream>>>(wkvb, xdsT, kbf, vtbf);
    k_fused<<<dim3(64, 8), 256, 0, stream>>>(wqb, xnT, kbf, vtbf, wob, x, gamma, out);
  }
}